// Round 1
// baseline (1894.039 us; speedup 1.0000x reference)
//
#include <hip/hip_runtime.h>
#include <hip/hip_bf16.h>

#define DDIM 1024
#define HDIM 4096
#define NEXP 8
#define NROW 8192

typedef __attribute__((ext_vector_type(8))) short s16x8;
typedef __attribute__((ext_vector_type(4))) float f32x4;

using bf16 = __hip_bfloat16;

// ---------------------------------------------------------------- helpers
__device__ inline void gload16(const bf16* g, bf16* lds) {
    // async global->LDS, 16B per lane; LDS dest = wave-uniform base + lane*16
    __builtin_amdgcn_global_load_lds(
        (const __attribute__((address_space(1))) unsigned int*)g,
        (__attribute__((address_space(3))) unsigned int*)lds,
        16, 0, 0);
}

// ---------------------------------------------------------------- x -> bf16
__global__ void cvt_x_kernel(const float* __restrict__ x, bf16* __restrict__ xb, int total4) {
    int i = blockIdx.x * 256 + threadIdx.x;
    if (i >= total4) return;
    float4 v = ((const float4*)x)[i];
    union { bf16 b[4]; uint2 u; } p;
    p.b[0] = __float2bfloat16(v.x);
    p.b[1] = __float2bfloat16(v.y);
    p.b[2] = __float2bfloat16(v.z);
    p.b[3] = __float2bfloat16(v.w);
    ((uint2*)xb)[i] = p.u;
}

// ------------------------------------------- fp32 [E][R][C] -> bf16 [E][C][R]
__global__ void transpose_cvt_kernel(const float* __restrict__ in, bf16* __restrict__ out,
                                     int R, int C) {
    __shared__ float tile[32][33];
    const size_t esz = (size_t)R * C;
    const float* src = in + (size_t)blockIdx.z * esz;
    bf16* dst = out + (size_t)blockIdx.z * esz;
    int c0 = blockIdx.x * 32, r0 = blockIdx.y * 32;
    int tx = threadIdx.x & 31, ty = threadIdx.x >> 5;   // 256 threads: 32 x 8
#pragma unroll
    for (int i = 0; i < 32; i += 8)
        tile[ty + i][tx] = src[(size_t)(r0 + ty + i) * C + (c0 + tx)];
    __syncthreads();
#pragma unroll
    for (int i = 0; i < 32; i += 8)
        dst[(size_t)(c0 + ty + i) * R + (r0 + tx)] = __float2bfloat16(tile[tx][ty + i]);
}

// ---------------------------------------------------------------- gate softmax
__global__ void gate_kernel(const float* __restrict__ x, const float* __restrict__ Wg,
                            const float* __restrict__ bg, float* __restrict__ wts) {
    int wave = threadIdx.x >> 6, lane = threadIdx.x & 63;
    int n = blockIdx.x * 4 + wave;
    const float* xr = x + (size_t)n * DDIM;
    float acc[NEXP] = {0.f, 0.f, 0.f, 0.f, 0.f, 0.f, 0.f, 0.f};
    for (int d = lane; d < DDIM; d += 64) {
        float xv = xr[d];
        const float* wr = Wg + (size_t)d * NEXP;
#pragma unroll
        for (int e = 0; e < NEXP; ++e) acc[e] += xv * wr[e];
    }
#pragma unroll
    for (int off = 32; off > 0; off >>= 1) {
#pragma unroll
        for (int e = 0; e < NEXP; ++e) acc[e] += __shfl_xor(acc[e], off, 64);
    }
    if (lane == 0) {
        float mx = -1e30f;
#pragma unroll
        for (int e = 0; e < NEXP; ++e) { acc[e] += bg[e]; mx = fmaxf(mx, acc[e]); }
        float s = 0.f;
#pragma unroll
        for (int e = 0; e < NEXP; ++e) { acc[e] = __expf(acc[e] - mx); s += acc[e]; }
        float inv = 1.0f / s;
#pragma unroll
        for (int e = 0; e < NEXP; ++e) wts[(size_t)n * NEXP + e] = acc[e] * inv;
    }
}

// ------------------------------------------- out[n,d] = sum_e w[n,e]*b2[e,d]
__global__ void out_init_kernel(const float* __restrict__ wts, const float* __restrict__ b2,
                                float* __restrict__ out) {
    size_t idx = (size_t)blockIdx.x * 256 + threadIdx.x;
    int d = (int)(idx & (DDIM - 1));
    size_t n = idx >> 10;
    const float* w = wts + n * NEXP;
    float s = 0.f;
#pragma unroll
    for (int e = 0; e < NEXP; ++e) s += w[e] * b2[(size_t)e * DDIM + d];
    out[idx] = s;
}

// ---------------------------------------------------------------- GEMM
// A [M][K] bf16 row-major (K contiguous); BT [Ncol][K] bf16 (K contiguous).
// MODE 1: Cout = bf16 H, epilogue relu(acc + bias[col])
// MODE 2: Cout = fp32 out, epilogue out += weights[row*8+expert] * acc
template <int MODE>
__global__ __launch_bounds__(256) void gemm_kernel(
    const bf16* __restrict__ A, const bf16* __restrict__ BT, void* __restrict__ Cout,
    const float* __restrict__ bias, const float* __restrict__ weights,
    int M, int Ncol, int K, int expert) {
    constexpr int BM = 128, BN = 128, BK = 32;
    __shared__ __align__(16) bf16 As[BM * BK];
    __shared__ __align__(16) bf16 Bs[BN * BK];
    const int tid = threadIdx.x;
    const int wave = tid >> 6, lane = tid & 63;
    const int wm = wave >> 1, wn = wave & 1;
    const size_t m0 = (size_t)blockIdx.y * BM;
    const size_t n0 = (size_t)blockIdx.x * BN;

    f32x4 acc[4][4];
#pragma unroll
    for (int m = 0; m < 4; ++m)
#pragma unroll
        for (int n = 0; n < 4; ++n) acc[m][n] = (f32x4){0.f, 0.f, 0.f, 0.f};

    const int r = lane & 15, kg = lane >> 4;
    const int nsteps = K / BK;
    for (int kt = 0; kt < nsteps; ++kt) {
        const int k0 = kt * BK;
        // stage A and B tiles (128 rows x 32 k, 64B rows); 512 chunks of 16B
#pragma unroll
        for (int j = 0; j < 2; ++j) {
            int c = (wave * 2 + j) * 64 + lane;
            int row = c >> 2, kc = c & 3;
            gload16(A + (m0 + row) * (size_t)K + k0 + kc * 8, As + (wave * 2 + j) * 512);
            gload16(BT + (n0 + row) * (size_t)K + k0 + kc * 8, Bs + (wave * 2 + j) * 512);
        }
        __syncthreads();
        s16x8 a[4], b[4];
#pragma unroll
        for (int m = 0; m < 4; ++m)
            a[m] = *(const s16x8*)&As[(wm * 64 + m * 16 + r) * BK + kg * 8];
#pragma unroll
        for (int n = 0; n < 4; ++n)
            b[n] = *(const s16x8*)&Bs[(wn * 64 + n * 16 + r) * BK + kg * 8];
#pragma unroll
        for (int m = 0; m < 4; ++m)
#pragma unroll
            for (int n = 0; n < 4; ++n)
                acc[m][n] = __builtin_amdgcn_mfma_f32_16x16x32_bf16(a[m], b[n], acc[m][n], 0, 0, 0);
        __syncthreads();
    }

    // epilogue: C/D layout col = lane&15, row = (lane>>4)*4 + j
    if (MODE == 1) {
        bf16* Hb = (bf16*)Cout;
#pragma unroll
        for (int n = 0; n < 4; ++n) {
            int col = (int)n0 + wn * 64 + n * 16 + r;
            float bv = bias[col];
#pragma unroll
            for (int m = 0; m < 4; ++m) {
#pragma unroll
                for (int j = 0; j < 4; ++j) {
                    int rr = wm * 64 + m * 16 + kg * 4 + j;
                    float v = acc[m][n][j] + bv;
                    v = v > 0.f ? v : 0.f;
                    Hb[(m0 + rr) * (size_t)Ncol + col] = __float2bfloat16(v);
                }
            }
        }
    } else {
        float* out = (float*)Cout;
#pragma unroll
        for (int m = 0; m < 4; ++m) {
#pragma unroll
            for (int j = 0; j < 4; ++j) {
                int rr = wm * 64 + m * 16 + kg * 4 + j;
                float wv = weights[(m0 + rr) * NEXP + expert];
#pragma unroll
                for (int n = 0; n < 4; ++n) {
                    int col = (int)n0 + wn * 64 + n * 16 + r;
                    size_t o = (m0 + rr) * (size_t)Ncol + col;
                    out[o] += wv * acc[m][n][j];
                }
            }
        }
    }
}

// ---------------------------------------------------------------- launch
extern "C" void kernel_launch(void* const* d_in, const int* in_sizes, int n_in,
                              void* d_out, int out_size, void* d_ws, size_t ws_size,
                              hipStream_t stream) {
    const float* x  = (const float*)d_in[0];
    const float* Wg = (const float*)d_in[1];
    const float* bg = (const float*)d_in[2];
    const float* W1 = (const float*)d_in[3];
    const float* b1 = (const float*)d_in[4];
    const float* W2 = (const float*)d_in[5];
    const float* b2 = (const float*)d_in[6];
    float* out = (float*)d_out;

    char* ws = (char*)d_ws;
    bf16* xb   = (bf16*)(ws);                          // 16 MiB  [N][D]
    bf16* W1T  = (bf16*)(ws + (16ull << 20));          // 64 MiB  [E][H][D]
    bf16* W2T  = (bf16*)(ws + (80ull << 20));          // 64 MiB  [E][D][H]
    bf16* Hb   = (bf16*)(ws + (144ull << 20));         // 64 MiB  [N][H] (one expert)
    float* wts = (float*)(ws + (208ull << 20));        // 256 KiB [N][E]

    cvt_x_kernel<<<(NROW * DDIM / 4 + 255) / 256, 256, 0, stream>>>(x, xb, NROW * DDIM / 4);
    transpose_cvt_kernel<<<dim3(HDIM / 32, DDIM / 32, NEXP), 256, 0, stream>>>(W1, W1T, DDIM, HDIM);
    transpose_cvt_kernel<<<dim3(DDIM / 32, HDIM / 32, NEXP), 256, 0, stream>>>(W2, W2T, HDIM, DDIM);
    gate_kernel<<<NROW / 4, 256, 0, stream>>>(x, Wg, bg, wts);
    out_init_kernel<<<NROW * DDIM / 256, 256, 0, stream>>>(wts, b2, out);

    for (int e = 0; e < NEXP; ++e) {
        gemm_kernel<1><<<dim3(HDIM / 128, NROW / 128), 256, 0, stream>>>(
            xb, W1T + (size_t)e * HDIM * DDIM, Hb, b1 + (size_t)e * HDIM, nullptr,
            NROW, HDIM, DDIM, e);
        gemm_kernel<2><<<dim3(DDIM / 128, NROW / 128), 256, 0, stream>>>(
            Hb, W2T + (size_t)e * DDIM * HDIM, out, nullptr, wts,
            NROW, DDIM, HDIM, e);
    }
}

// Round 2
// 1859.412 us; speedup vs baseline: 1.0186x; 1.0186x over previous
//
#include <hip/hip_runtime.h>
#include <hip/hip_bf16.h>

#define DDIM 1024
#define HDIM 4096
#define NEXP 8
#define NROW 8192

typedef __attribute__((ext_vector_type(8))) short s16x8;
typedef __attribute__((ext_vector_type(4))) float f32x4;

using bf16 = __hip_bfloat16;

// ---------------------------------------------------------------- helpers
__device__ __forceinline__ void gload16(const bf16* g, bf16* lds) {
    // async global->LDS, 16B per lane; LDS dest = wave-uniform base + lane*16
    __builtin_amdgcn_global_load_lds(
        (const __attribute__((address_space(1))) unsigned int*)g,
        (__attribute__((address_space(3))) unsigned int*)lds,
        16, 0, 0);
}

template <int N>
__device__ __forceinline__ void wait_vmcnt() {
    if constexpr (N >= 8)      asm volatile("s_waitcnt vmcnt(8)" ::: "memory");
    else if constexpr (N == 6) asm volatile("s_waitcnt vmcnt(6)" ::: "memory");
    else if constexpr (N == 4) asm volatile("s_waitcnt vmcnt(4)" ::: "memory");
    else if constexpr (N == 3) asm volatile("s_waitcnt vmcnt(3)" ::: "memory");
    else                       asm volatile("s_waitcnt vmcnt(0)" ::: "memory");
}

// ---------------------------------------------------------------- x -> bf16
__global__ void cvt_x_kernel(const float* __restrict__ x, bf16* __restrict__ xb, int total4) {
    int i = blockIdx.x * 256 + threadIdx.x;
    if (i >= total4) return;
    float4 v = ((const float4*)x)[i];
    union { bf16 b[4]; uint2 u; } p;
    p.b[0] = __float2bfloat16(v.x);
    p.b[1] = __float2bfloat16(v.y);
    p.b[2] = __float2bfloat16(v.z);
    p.b[3] = __float2bfloat16(v.w);
    ((uint2*)xb)[i] = p.u;
}

// ------------------------------------------- fp32 [E][R][C] -> bf16 [E][C][R]
__global__ void transpose_cvt_kernel(const float* __restrict__ in, bf16* __restrict__ out,
                                     int R, int C) {
    __shared__ float tile[32][33];
    const size_t esz = (size_t)R * C;
    const float* src = in + (size_t)blockIdx.z * esz;
    bf16* dst = out + (size_t)blockIdx.z * esz;
    int c0 = blockIdx.x * 32, r0 = blockIdx.y * 32;
    int tx = threadIdx.x & 31, ty = threadIdx.x >> 5;   // 256 threads: 32 x 8
#pragma unroll
    for (int i = 0; i < 32; i += 8)
        tile[ty + i][tx] = src[(size_t)(r0 + ty + i) * C + (c0 + tx)];
    __syncthreads();
#pragma unroll
    for (int i = 0; i < 32; i += 8)
        dst[(size_t)(c0 + ty + i) * R + (r0 + tx)] = __float2bfloat16(tile[tx][ty + i]);
}

// ---------------------------------------------------------------- gate softmax
__global__ void gate_kernel(const float* __restrict__ x, const float* __restrict__ Wg,
                            const float* __restrict__ bg, float* __restrict__ wts) {
    int wave = threadIdx.x >> 6, lane = threadIdx.x & 63;
    int n = blockIdx.x * 4 + wave;
    const float* xr = x + (size_t)n * DDIM;
    float acc[NEXP] = {0.f, 0.f, 0.f, 0.f, 0.f, 0.f, 0.f, 0.f};
    for (int d = lane; d < DDIM; d += 64) {
        float xv = xr[d];
        const float* wr = Wg + (size_t)d * NEXP;
#pragma unroll
        for (int e = 0; e < NEXP; ++e) acc[e] += xv * wr[e];
    }
#pragma unroll
    for (int off = 32; off > 0; off >>= 1) {
#pragma unroll
        for (int e = 0; e < NEXP; ++e) acc[e] += __shfl_xor(acc[e], off, 64);
    }
    if (lane == 0) {
        float mx = -1e30f;
#pragma unroll
        for (int e = 0; e < NEXP; ++e) { acc[e] += bg[e]; mx = fmaxf(mx, acc[e]); }
        float s = 0.f;
#pragma unroll
        for (int e = 0; e < NEXP; ++e) { acc[e] = __expf(acc[e] - mx); s += acc[e]; }
        float inv = 1.0f / s;
#pragma unroll
        for (int e = 0; e < NEXP; ++e) wts[(size_t)n * NEXP + e] = acc[e] * inv;
    }
}

// ------------------------------------------- out[n,d] = sum_e w[n,e]*b2[e,d]
__global__ void out_init_kernel(const float* __restrict__ wts, const float* __restrict__ b2,
                                float* __restrict__ out) {
    size_t idx = (size_t)blockIdx.x * 256 + threadIdx.x;
    int d = (int)(idx & (DDIM - 1));
    size_t n = idx >> 10;
    const float* w = wts + n * NEXP;
    float s = 0.f;
#pragma unroll
    for (int e = 0; e < NEXP; ++e) s += w[e] * b2[(size_t)e * DDIM + d];
    out[idx] = s;
}

// ---------------------------------------------------------------- GEMM (8-wave, ring-4, counted vmcnt)
// Tile: BM=256 x BN=NF*64, BK=32. 8 waves as 2(M) x 4(N); per-wave 128 x NF*16.
// A [M][K] bf16 (K contig, lda); BT [Ncol][K] bf16 (K contig, ldb).
// LDS: ring of 4 buffers, each A-tile 256x32 + B-tile BNx32, XOR-swizzled
// (inverse swizzle on global source since global_load_lds writes linearly).
// MODE 1: Cout bf16 H, epilogue relu(acc + bias[col])
// MODE 2: Cout fp32 out, epilogue out += wts[row*8+expert] * acc
template <int NF, int MODE>
__global__ __launch_bounds__(512, 2) void gemm8(
    const bf16* __restrict__ A, const bf16* __restrict__ BT, void* __restrict__ Cout,
    const float* __restrict__ bias, const float* __restrict__ wts,
    int lda, int ldb, int ldc, int NT, int tilesM, int expert) {
    constexpr int BN = NF * 64;
    constexpr int BIN = (BN * 4) / 512;     // B stage insts per thread (2 or 1)
    constexpr int LPT = 2 + BIN;            // stage insts per thread per K-tile
    constexpr int AELEMS = 256 * 32;        // 8192 bf16
    constexpr int BELEMS = BN * 32;
    __shared__ __align__(16) bf16 lds[4][AELEMS + BELEMS];

    const int tid = threadIdx.x;
    const int wave = tid >> 6, lane = tid & 63;
    const int wm = wave >> 2, wn = wave & 3;
    const int r = lane & 15, kg = lane >> 4;

    // bijective XCD swizzle (nwg % 8 == 0 by construction)
    const int nwg = gridDim.x;
    const int orig = blockIdx.x;
    const int wgid = (orig & 7) * (nwg >> 3) + (orig >> 3);
    const int tm = wgid % tilesM, tn = wgid / tilesM;

    const bf16* gA = A + (size_t)tm * 256 * lda;
    const bf16* gB = BT + (size_t)tn * BN * ldb;

    f32x4 acc[8][NF];
#pragma unroll
    for (int m = 0; m < 8; ++m)
#pragma unroll
        for (int n = 0; n < NF; ++n) acc[m][n] = (f32x4){0.f, 0.f, 0.f, 0.f};

    // stage one K-tile's A (or B) into ring buffer t&3.
    // LDS chunk c (16B) holds global row R=c>>2, k-chunk kc=(c&3)^(R&3)  [inverse swizzle]
    auto stageA = [&](int t) {
        bf16* Ab = lds[t & 3];
#pragma unroll
        for (int j = 0; j < 2; ++j) {
            int cw = (wave * 2 + j) * 64 + lane;
            int R = cw >> 2, kc = (cw & 3) ^ (R & 3);
            gload16(gA + (size_t)R * lda + t * 32 + kc * 8, Ab + (wave * 2 + j) * 512);
        }
    };
    auto stageB = [&](int t) {
        bf16* Bb = lds[t & 3] + AELEMS;
#pragma unroll
        for (int j = 0; j < BIN; ++j) {
            int cw = (wave * BIN + j) * 64 + lane;
            int R = cw >> 2, kc = (cw & 3) ^ (R & 3);
            gload16(gB + (size_t)R * ldb + t * 32 + kc * 8, Bb + (wave * BIN + j) * 512);
        }
    };

    // prologue: prefetch tiles 0,1,2
    stageA(0); stageB(0);
    stageA(1); stageB(1);
    stageA(2); stageB(2);
    wait_vmcnt<2 * LPT>();                  // tile 0 resident; 1,2 in flight
    __builtin_amdgcn_s_barrier();

    for (int t = 0; t < NT; ++t) {
        const bf16* Ab = lds[t & 3];
        const bf16* Bb = Ab + AELEMS;
        s16x8 afr[4], bfr[NF];

        // ---- phase 0: read B(all) + A rows 0..63 of wave panel; stage A(t+3)
#pragma unroll
        for (int n = 0; n < NF; ++n) {
            int R = wn * (NF * 16) + n * 16 + r;
            bfr[n] = *(const s16x8*)(Bb + R * 32 + ((kg * 8) ^ ((R & 3) << 3)));
        }
#pragma unroll
        for (int m = 0; m < 4; ++m) {
            int R = wm * 128 + m * 16 + r;
            afr[m] = *(const s16x8*)(Ab + R * 32 + ((kg * 8) ^ ((R & 3) << 3)));
        }
        if (t + 3 < NT) stageA(t + 3);
        __builtin_amdgcn_s_barrier();
        asm volatile("s_waitcnt lgkmcnt(0)" ::: "memory");
        __builtin_amdgcn_sched_barrier(0);
        __builtin_amdgcn_s_setprio(1);
#pragma unroll
        for (int m = 0; m < 4; ++m)
#pragma unroll
            for (int n = 0; n < NF; ++n)
                acc[m][n] = __builtin_amdgcn_mfma_f32_16x16x32_bf16(afr[m], bfr[n], acc[m][n], 0, 0, 0);
        __builtin_amdgcn_s_setprio(0);
        __builtin_amdgcn_s_barrier();

        // ---- phase 1: read A rows 64..127 of wave panel; stage B(t+3)
#pragma unroll
        for (int m = 0; m < 4; ++m) {
            int R = wm * 128 + (m + 4) * 16 + r;
            afr[m] = *(const s16x8*)(Ab + R * 32 + ((kg * 8) ^ ((R & 3) << 3)));
        }
        if (t + 3 < NT) stageB(t + 3);
        __builtin_amdgcn_s_barrier();
        asm volatile("s_waitcnt lgkmcnt(0)" ::: "memory");
        __builtin_amdgcn_sched_barrier(0);
        __builtin_amdgcn_s_setprio(1);
#pragma unroll
        for (int m = 0; m < 4; ++m)
#pragma unroll
            for (int n = 0; n < NF; ++n)
                acc[m + 4][n] = __builtin_amdgcn_mfma_f32_16x16x32_bf16(afr[m], bfr[n], acc[m + 4][n], 0, 0, 0);
        __builtin_amdgcn_s_setprio(0);

        // ---- K-tile boundary: counted drain for tile t+1 (never 0 mid-loop)
        if (t + 1 < NT) {
            if (t + 1 < NT - 2)       wait_vmcnt<2 * LPT>();
            else if (t + 1 == NT - 2) wait_vmcnt<LPT>();
            else                      wait_vmcnt<0>();
            __builtin_amdgcn_s_barrier();
        }
    }

    // ---- epilogue. C/D layout: col = lane&15 (r), row = kg*4 + j
    const size_t row0 = (size_t)tm * 256 + wm * 128;
    const int col0 = tn * BN + wn * (NF * 16);
    if (MODE == 1) {
        bf16* H = (bf16*)Cout;
#pragma unroll
        for (int n = 0; n < NF; ++n) {
            int cc = col0 + n * 16 + r;
            float bv = bias[cc];
#pragma unroll
            for (int m = 0; m < 8; ++m) {
#pragma unroll
                for (int j = 0; j < 4; ++j) {
                    size_t rr = row0 + m * 16 + kg * 4 + j;
                    float v = acc[m][n][j] + bv;
                    v = v > 0.f ? v : 0.f;
                    H[rr * (size_t)ldc + cc] = __float2bfloat16(v);
                }
            }
        }
    } else {
        float* O = (float*)Cout;
#pragma unroll
        for (int m = 0; m < 8; ++m) {
#pragma unroll
            for (int j = 0; j < 4; ++j) {
                size_t rr = row0 + m * 16 + kg * 4 + j;
                float wv = wts[rr * NEXP + expert];
#pragma unroll
                for (int n = 0; n < NF; ++n) {
                    int cc = col0 + n * 16 + r;
                    O[rr * (size_t)ldc + cc] += wv * acc[m][n][j];
                }
            }
        }
    }
}

// ---------------------------------------------------------------- launch
extern "C" void kernel_launch(void* const* d_in, const int* in_sizes, int n_in,
                              void* d_out, int out_size, void* d_ws, size_t ws_size,
                              hipStream_t stream) {
    const float* x  = (const float*)d_in[0];
    const float* Wg = (const float*)d_in[1];
    const float* bg = (const float*)d_in[2];
    const float* W1 = (const float*)d_in[3];
    const float* b1 = (const float*)d_in[4];
    const float* W2 = (const float*)d_in[5];
    const float* b2 = (const float*)d_in[6];
    float* out = (float*)d_out;

    char* ws = (char*)d_ws;
    bf16* xb   = (bf16*)(ws);                          // 16 MiB  [N][D]
    bf16* W1T  = (bf16*)(ws + (16ull << 20));          // 64 MiB  [E][H][D]
    bf16* W2T  = (bf16*)(ws + (80ull << 20));          // 64 MiB  [E][D][H]
    bf16* Hb   = (bf16*)(ws + (144ull << 20));         // 64 MiB  [N][H] (one expert)
    float* wts = (float*)(ws + (208ull << 20));        // 256 KiB [N][E]

    cvt_x_kernel<<<(NROW * DDIM / 4 + 255) / 256, 256, 0, stream>>>(x, xb, NROW * DDIM / 4);
    transpose_cvt_kernel<<<dim3(HDIM / 32, DDIM / 32, NEXP), 256, 0, stream>>>(W1, W1T, DDIM, HDIM);
    transpose_cvt_kernel<<<dim3(DDIM / 32, HDIM / 32, NEXP), 256, 0, stream>>>(W2, W2T, HDIM, DDIM);
    gate_kernel<<<NROW / 4, 256, 0, stream>>>(x, Wg, bg, wts);
    out_init_kernel<<<NROW * DDIM / 256, 256, 0, stream>>>(wts, b2, out);

    for (int e = 0; e < NEXP; ++e) {
        // GEMM1: M=8192, N=4096, K=1024  -> grid 32x16 = 512 blocks (BN=256)
        gemm8<4, 1><<<512, 512, 0, stream>>>(
            xb, W1T + (size_t)e * HDIM * DDIM, Hb, b1 + (size_t)e * HDIM, nullptr,
            DDIM, DDIM, HDIM, DDIM / 32, 32, e);
        // GEMM2: M=8192, N=1024, K=4096  -> grid 32x8 = 256 blocks (BN=128)
        gemm8<2, 2><<<256, 512, 0, stream>>>(
            Hb, W2T + (size_t)e * DDIM * HDIM, out, nullptr, wts,
            HDIM, HDIM, DDIM, HDIM / 32, 32, e);
    }
}

// Round 3
// 1437.589 us; speedup vs baseline: 1.3175x; 1.2934x over previous
//
#include <hip/hip_runtime.h>
#include <hip/hip_bf16.h>

#define DDIM 1024
#define HDIM 4096
#define NEXP 8
#define NROW 8192

typedef __attribute__((ext_vector_type(8))) short s16x8;
typedef __attribute__((ext_vector_type(4))) float f32x4;

using bf16 = __hip_bfloat16;

// ---------------------------------------------------------------- helpers
__device__ __forceinline__ void gload16(const bf16* g, bf16* lds) {
    __builtin_amdgcn_global_load_lds(
        (const __attribute__((address_space(1))) unsigned int*)g,
        (__attribute__((address_space(3))) unsigned int*)lds,
        16, 0, 0);
}

template <int N>
__device__ __forceinline__ void wait_vmcnt() {
    if constexpr (N >= 6)      asm volatile("s_waitcnt vmcnt(6)" ::: "memory");
    else if constexpr (N == 3) asm volatile("s_waitcnt vmcnt(3)" ::: "memory");
    else                       asm volatile("s_waitcnt vmcnt(0)" ::: "memory");
}

// ---------------------------------------------------------------- x -> bf16
__global__ void cvt_x_kernel(const float* __restrict__ x, bf16* __restrict__ xb, int total4) {
    int i = blockIdx.x * 256 + threadIdx.x;
    if (i >= total4) return;
    float4 v = ((const float4*)x)[i];
    union { bf16 b[4]; uint2 u; } p;
    p.b[0] = __float2bfloat16(v.x);
    p.b[1] = __float2bfloat16(v.y);
    p.b[2] = __float2bfloat16(v.z);
    p.b[3] = __float2bfloat16(v.w);
    ((uint2*)xb)[i] = p.u;
}

// ------------------------------------------- fp32 [E][R][C] -> bf16 [E][C][R]
__global__ void transpose_cvt_kernel(const float* __restrict__ in, bf16* __restrict__ out,
                                     int R, int C) {
    __shared__ float tile[32][33];
    const size_t esz = (size_t)R * C;
    const float* src = in + (size_t)blockIdx.z * esz;
    bf16* dst = out + (size_t)blockIdx.z * esz;
    int c0 = blockIdx.x * 32, r0 = blockIdx.y * 32;
    int tx = threadIdx.x & 31, ty = threadIdx.x >> 5;   // 256 threads: 32 x 8
#pragma unroll
    for (int i = 0; i < 32; i += 8)
        tile[ty + i][tx] = src[(size_t)(r0 + ty + i) * C + (c0 + tx)];
    __syncthreads();
#pragma unroll
    for (int i = 0; i < 32; i += 8)
        dst[(size_t)(c0 + ty + i) * R + (r0 + tx)] = __float2bfloat16(tile[tx][ty + i]);
}

// ---------------------------------------------------------------- gate softmax
__global__ void gate_kernel(const float* __restrict__ x, const float* __restrict__ Wg,
                            const float* __restrict__ bg, float* __restrict__ wts) {
    int wave = threadIdx.x >> 6, lane = threadIdx.x & 63;
    int n = blockIdx.x * 4 + wave;
    const float* xr = x + (size_t)n * DDIM;
    float acc[NEXP] = {0.f, 0.f, 0.f, 0.f, 0.f, 0.f, 0.f, 0.f};
    for (int d = lane; d < DDIM; d += 64) {
        float xv = xr[d];
        const float* wr = Wg + (size_t)d * NEXP;
#pragma unroll
        for (int e = 0; e < NEXP; ++e) acc[e] += xv * wr[e];
    }
#pragma unroll
    for (int off = 32; off > 0; off >>= 1) {
#pragma unroll
        for (int e = 0; e < NEXP; ++e) acc[e] += __shfl_xor(acc[e], off, 64);
    }
    if (lane == 0) {
        float mx = -1e30f;
#pragma unroll
        for (int e = 0; e < NEXP; ++e) { acc[e] += bg[e]; mx = fmaxf(mx, acc[e]); }
        float s = 0.f;
#pragma unroll
        for (int e = 0; e < NEXP; ++e) { acc[e] = __expf(acc[e] - mx); s += acc[e]; }
        float inv = 1.0f / s;
#pragma unroll
        for (int e = 0; e < NEXP; ++e) wts[(size_t)n * NEXP + e] = acc[e] * inv;
    }
}

// ------------------------------------------- out[n,d] = sum_e w[n,e]*b2[e,d]
__global__ void out_init_kernel(const float* __restrict__ wts, const float* __restrict__ b2,
                                float* __restrict__ out) {
    size_t idx = (size_t)blockIdx.x * 256 + threadIdx.x;
    int d = (int)(idx & (DDIM - 1));
    size_t n = idx >> 10;
    const float* w = wts + n * NEXP;
    float s = 0.f;
#pragma unroll
    for (int e = 0; e < NEXP; ++e) s += w[e] * b2[(size_t)e * DDIM + d];
    out[idx] = s;
}

// ---------------------------------------------------------------- GEMM
// Tile BM=256 x BN=128, BK=32. 8 waves = 2(M) x 4(N); per-wave 128 x 32 out.
// A [M][K] bf16 (K contig, lda); BT [Ncol][K] bf16 (K contig, ldb).
// Ring-3 LDS (72 KiB -> 2 blocks/CU), counted vmcnt (never 0 mid-loop).
// LDS bank swizzle: 16B chunk col = kg ^ ((R>>1)&3)  (2-way max = free);
// global_load_lds writes linearly, so the INVERSE swizzle is applied to the
// global source k-chunk (both-sides-or-neither, rule #21).
// 2-D XCD mapping: xcd = blockIdx&7 owns a rect of (tilesM/XGM) x (tilesN/XGN)
// tiles, walked in 4x8 sub-rectangles so concurrent blocks share L2 panels.
// MODE 1: Cout bf16 H, epilogue relu(acc + bias[col])
// MODE 2: Cout fp32 out, epilogue out += wts[row*8+expert] * acc
template <int MODE>
__global__ __launch_bounds__(512, 4) void gemm8(
    const bf16* __restrict__ A, const bf16* __restrict__ BT, void* __restrict__ Cout,
    const float* __restrict__ bias, const float* __restrict__ wts,
    int lda, int ldb, int ldc, int NT, int tilesM, int tilesN, int XGN, int expert) {
    constexpr int LPT = 3;                  // stage insts / thread / K-tile (2 A + 1 B)
    constexpr int AELEMS = 256 * 32;        // 16 KiB
    constexpr int BELEMS = 128 * 32;        // 8 KiB
    __shared__ __align__(16) bf16 lds[3][AELEMS + BELEMS];

    const int tid = threadIdx.x;
    const int wave = tid >> 6, lane = tid & 63;
    const int wm = wave >> 2, wn = wave & 3;
    const int r = lane & 15, kg = lane >> 4;

    // ---- 2-D XCD-aware tile mapping
    const int xcd = blockIdx.x & 7, slot = blockIdx.x >> 3;
    const int XGM = 8 / XGN;
    const int rm = tilesM / XGM, rn = tilesN / XGN;
    const int g = slot >> 5, u = slot & 31;
    const int gpr = rn >> 3;                // 4x8 groups per row-band
    const int gm = (g / gpr) * 4 + (u >> 3);
    const int gn = (g % gpr) * 8 + (u & 7);
    const int tm = (xcd / XGN) * rm + gm;
    const int tn = (xcd % XGN) * rn + gn;

    const bf16* gA = A + (size_t)tm * 256 * lda;
    const bf16* gB = BT + (size_t)tn * 128 * ldb;

    f32x4 acc[8][2];
#pragma unroll
    for (int m = 0; m < 8; ++m)
#pragma unroll
        for (int n = 0; n < 2; ++n) acc[m][n] = (f32x4){0.f, 0.f, 0.f, 0.f};

    auto stageA = [&](int t) {
        bf16* Ab = lds[t % 3];
#pragma unroll
        for (int j = 0; j < 2; ++j) {
            int cw = (wave * 2 + j) * 64 + lane;
            int R = cw >> 2, kc = (cw & 3) ^ ((R >> 1) & 3);
            gload16(gA + (size_t)R * lda + t * 32 + kc * 8, Ab + (wave * 2 + j) * 512);
        }
    };
    auto stageB = [&](int t) {
        bf16* Bb = lds[t % 3] + AELEMS;
        int cw = wave * 64 + lane;
        int R = cw >> 2, kc = (cw & 3) ^ ((R >> 1) & 3);
        gload16(gB + (size_t)R * ldb + t * 32 + kc * 8, Bb + wave * 512);
    };

    // prologue: prefetch tiles 0,1
    stageA(0); stageB(0);
    stageA(1); stageB(1);
    wait_vmcnt<LPT>();                      // tile 0 resident; tile 1 in flight
    __builtin_amdgcn_s_barrier();

    for (int t = 0; t < NT; ++t) {
        const bf16* Ab = lds[t % 3];
        const bf16* Bb = Ab + AELEMS;
        s16x8 afr[4], bfr[2];

        // ---- phase 0: read B + A rows 0..63 of wave panel; stage A(t+2)
#pragma unroll
        for (int n = 0; n < 2; ++n) {
            int R = wn * 32 + n * 16 + r;
            bfr[n] = *(const s16x8*)(Bb + R * 32 + ((kg ^ ((R >> 1) & 3)) * 8));
        }
#pragma unroll
        for (int m = 0; m < 4; ++m) {
            int R = wm * 128 + m * 16 + r;
            afr[m] = *(const s16x8*)(Ab + R * 32 + ((kg ^ ((R >> 1) & 3)) * 8));
        }
        if (t + 2 < NT) stageA(t + 2);
        __builtin_amdgcn_s_barrier();
        asm volatile("s_waitcnt lgkmcnt(0)" ::: "memory");
        __builtin_amdgcn_sched_barrier(0);
        __builtin_amdgcn_s_setprio(1);
#pragma unroll
        for (int m = 0; m < 4; ++m)
#pragma unroll
            for (int n = 0; n < 2; ++n)
                acc[m][n] = __builtin_amdgcn_mfma_f32_16x16x32_bf16(afr[m], bfr[n], acc[m][n], 0, 0, 0);
        __builtin_amdgcn_s_setprio(0);
        __builtin_amdgcn_s_barrier();

        // ---- phase 1: read A rows 64..127 of wave panel; stage B(t+2)
#pragma unroll
        for (int m = 0; m < 4; ++m) {
            int R = wm * 128 + (m + 4) * 16 + r;
            afr[m] = *(const s16x8*)(Ab + R * 32 + ((kg ^ ((R >> 1) & 3)) * 8));
        }
        if (t + 2 < NT) stageB(t + 2);
        __builtin_amdgcn_s_barrier();
        asm volatile("s_waitcnt lgkmcnt(0)" ::: "memory");
        __builtin_amdgcn_sched_barrier(0);
        __builtin_amdgcn_s_setprio(1);
#pragma unroll
        for (int m = 0; m < 4; ++m)
#pragma unroll
            for (int n = 0; n < 2; ++n)
                acc[m + 4][n] = __builtin_amdgcn_mfma_f32_16x16x32_bf16(afr[m], bfr[n], acc[m + 4][n], 0, 0, 0);
        __builtin_amdgcn_s_setprio(0);

        // ---- K-tile boundary: counted drain for tile t+1 (never 0 mid-loop)
        if (t + 1 < NT) {
            if (t + 2 < NT) wait_vmcnt<LPT>();
            else            wait_vmcnt<0>();
            __builtin_amdgcn_s_barrier();
        }
    }

    // ---- epilogue. C/D layout: col = lane&15 (r), row = kg*4 + j
    const size_t row0 = (size_t)tm * 256 + wm * 128;
    const int col0 = tn * 128 + wn * 32;
    if (MODE == 1) {
        bf16* H = (bf16*)Cout;
#pragma unroll
        for (int n = 0; n < 2; ++n) {
            int cc = col0 + n * 16 + r;
            float bv = bias[cc];
#pragma unroll
            for (int m = 0; m < 8; ++m) {
#pragma unroll
                for (int j = 0; j < 4; ++j) {
                    size_t rr = row0 + m * 16 + kg * 4 + j;
                    float v = acc[m][n][j] + bv;
                    v = v > 0.f ? v : 0.f;
                    H[rr * (size_t)ldc + cc] = __float2bfloat16(v);
                }
            }
        }
    } else {
        float* O = (float*)Cout;
#pragma unroll
        for (int m = 0; m < 8; ++m) {
#pragma unroll
            for (int j = 0; j < 4; ++j) {
                size_t rr = row0 + m * 16 + kg * 4 + j;
                float wv = wts[rr * NEXP + expert];
#pragma unroll
                for (int n = 0; n < 2; ++n) {
                    int cc = col0 + n * 16 + r;
                    O[rr * (size_t)ldc + cc] += wv * acc[m][n][j];
                }
            }
        }
    }
}

// ---------------------------------------------------------------- launch
extern "C" void kernel_launch(void* const* d_in, const int* in_sizes, int n_in,
                              void* d_out, int out_size, void* d_ws, size_t ws_size,
                              hipStream_t stream) {
    const float* x  = (const float*)d_in[0];
    const float* Wg = (const float*)d_in[1];
    const float* bg = (const float*)d_in[2];
    const float* W1 = (const float*)d_in[3];
    const float* b1 = (const float*)d_in[4];
    const float* W2 = (const float*)d_in[5];
    const float* b2 = (const float*)d_in[6];
    float* out = (float*)d_out;

    char* ws = (char*)d_ws;
    bf16* xb   = (bf16*)(ws);                          // 16 MiB  [N][D]
    bf16* W1T  = (bf16*)(ws + (16ull << 20));          // 64 MiB  [E][H][D]
    bf16* W2T  = (bf16*)(ws + (80ull << 20));          // 64 MiB  [E][D][H]
    bf16* Hb   = (bf16*)(ws + (144ull << 20));         // 64 MiB  [N][H] (one expert)
    float* wts = (float*)(ws + (208ull << 20));        // 256 KiB [N][E]

    cvt_x_kernel<<<(NROW * DDIM / 4 + 255) / 256, 256, 0, stream>>>(x, xb, NROW * DDIM / 4);
    transpose_cvt_kernel<<<dim3(HDIM / 32, DDIM / 32, NEXP), 256, 0, stream>>>(W1, W1T, DDIM, HDIM);
    transpose_cvt_kernel<<<dim3(DDIM / 32, HDIM / 32, NEXP), 256, 0, stream>>>(W2, W2T, HDIM, DDIM);
    gate_kernel<<<NROW / 4, 256, 0, stream>>>(x, Wg, bg, wts);
    out_init_kernel<<<NROW * DDIM / 256, 256, 0, stream>>>(wts, b2, out);

    for (int e = 0; e < NEXP; ++e) {
        // GEMM1: M=8192, N=4096, K=1024 -> 32x32 tiles = 1024 blocks; XCD rect 8x16
        gemm8<1><<<1024, 512, 0, stream>>>(
            xb, W1T + (size_t)e * HDIM * DDIM, Hb, b1 + (size_t)e * HDIM, nullptr,
            DDIM, DDIM, HDIM, DDIM / 32, 32, 32, 2, e);
        // GEMM2: M=8192, N=1024, K=4096 -> 32x8 tiles = 256 blocks; XCD rect 4x8
        gemm8<2><<<256, 512, 0, stream>>>(
            Hb, W2T + (size_t)e * DDIM * HDIM, out, nullptr, wts,
            HDIM, HDIM, DDIM, HDIM / 32, 32, 8, 1, e);
    }
}

// Round 4
// 1411.002 us; speedup vs baseline: 1.3423x; 1.0188x over previous
//
#include <hip/hip_runtime.h>
#include <hip/hip_bf16.h>

#define DDIM 1024
#define HDIM 4096
#define NEXP 8
#define NROW 8192

typedef __attribute__((ext_vector_type(8))) short s16x8;
typedef __attribute__((ext_vector_type(4))) float f32x4;

using bf16 = __hip_bfloat16;

// ---------------------------------------------------------------- helpers
__device__ __forceinline__ void gload16(const bf16* g, bf16* lds) {
    __builtin_amdgcn_global_load_lds(
        (const __attribute__((address_space(1))) unsigned int*)g,
        (__attribute__((address_space(3))) unsigned int*)lds,
        16, 0, 0);
}

template <int N>
__device__ __forceinline__ void wait_vmcnt() {
    if constexpr (N == 4)      asm volatile("s_waitcnt vmcnt(4)" ::: "memory");
    else if constexpr (N == 3) asm volatile("s_waitcnt vmcnt(3)" ::: "memory");
    else                       asm volatile("s_waitcnt vmcnt(0)" ::: "memory");
}

// ---------------------------------------------------------------- x -> bf16
__global__ void cvt_x_kernel(const float* __restrict__ x, bf16* __restrict__ xb, int total4) {
    int i = blockIdx.x * 256 + threadIdx.x;
    if (i >= total4) return;
    float4 v = ((const float4*)x)[i];
    union { bf16 b[4]; uint2 u; } p;
    p.b[0] = __float2bfloat16(v.x);
    p.b[1] = __float2bfloat16(v.y);
    p.b[2] = __float2bfloat16(v.z);
    p.b[3] = __float2bfloat16(v.w);
    ((uint2*)xb)[i] = p.u;
}

// ------------------------------------------- fp32 [E][R][C] -> bf16 [E][C][R]
__global__ void transpose_cvt_kernel(const float* __restrict__ in, bf16* __restrict__ out,
                                     int R, int C) {
    __shared__ float tile[32][33];
    const size_t esz = (size_t)R * C;
    const float* src = in + (size_t)blockIdx.z * esz;
    bf16* dst = out + (size_t)blockIdx.z * esz;
    int c0 = blockIdx.x * 32, r0 = blockIdx.y * 32;
    int tx = threadIdx.x & 31, ty = threadIdx.x >> 5;   // 256 threads: 32 x 8
#pragma unroll
    for (int i = 0; i < 32; i += 8)
        tile[ty + i][tx] = src[(size_t)(r0 + ty + i) * C + (c0 + tx)];
    __syncthreads();
#pragma unroll
    for (int i = 0; i < 32; i += 8)
        dst[(size_t)(c0 + ty + i) * R + (r0 + tx)] = __float2bfloat16(tile[tx][ty + i]);
}

// ---------------------------------------------------------------- gate softmax
__global__ void gate_kernel(const float* __restrict__ x, const float* __restrict__ Wg,
                            const float* __restrict__ bg, float* __restrict__ wts) {
    int wave = threadIdx.x >> 6, lane = threadIdx.x & 63;
    int n = blockIdx.x * 4 + wave;
    const float* xr = x + (size_t)n * DDIM;
    float acc[NEXP] = {0.f, 0.f, 0.f, 0.f, 0.f, 0.f, 0.f, 0.f};
    for (int d = lane; d < DDIM; d += 64) {
        float xv = xr[d];
        const float* wr = Wg + (size_t)d * NEXP;
#pragma unroll
        for (int e = 0; e < NEXP; ++e) acc[e] += xv * wr[e];
    }
#pragma unroll
    for (int off = 32; off > 0; off >>= 1) {
#pragma unroll
        for (int e = 0; e < NEXP; ++e) acc[e] += __shfl_xor(acc[e], off, 64);
    }
    if (lane == 0) {
        float mx = -1e30f;
#pragma unroll
        for (int e = 0; e < NEXP; ++e) { acc[e] += bg[e]; mx = fmaxf(mx, acc[e]); }
        float s = 0.f;
#pragma unroll
        for (int e = 0; e < NEXP; ++e) { acc[e] = __expf(acc[e] - mx); s += acc[e]; }
        float inv = 1.0f / s;
#pragma unroll
        for (int e = 0; e < NEXP; ++e) wts[(size_t)n * NEXP + e] = acc[e] * inv;
    }
}

// ------------------------------------------- out[n,d] = sum_e w[n,e]*b2[e,d]
__global__ void out_init_kernel(const float* __restrict__ wts, const float* __restrict__ b2,
                                float* __restrict__ out) {
    size_t idx = (size_t)blockIdx.x * 256 + threadIdx.x;
    int d = (int)(idx & (DDIM - 1));
    size_t n = idx >> 10;
    const float* w = wts + n * NEXP;
    float s = 0.f;
#pragma unroll
    for (int e = 0; e < NEXP; ++e) s += w[e] * b2[(size_t)e * DDIM + d];
    out[idx] = s;
}

// ---------------------------------------------------------------- GEMM
// BM=256, BN=NR*32 (NR=8 -> 256, NR=4 -> 128), BK=32. 8 waves = 4(M) x 2(N);
// per-wave 64 x NR*16. Per K-tile: NR*4 MFMA split into NPH phases of 16.
// Ring-3 LDS, counted vmcnt (never 0 mid-loop), proven 0-conflict swizzle:
//   16B chunk col = kg ^ ((R>>1)&3); inverse applied on global source.
// 2-D XCD tile mapping (round-3, FETCH-verified).
// MODE 1: Cout bf16 H, relu(acc + bias[col]); MODE 2: fp32 out += wts*acc.
template <int NR, int NPH, int MODE>
__global__ __launch_bounds__(512, 2) void gemm8(
    const bf16* __restrict__ A, const bf16* __restrict__ BT, void* __restrict__ Cout,
    const float* __restrict__ bias, const float* __restrict__ wts,
    int lda, int ldb, int ldc, int NT, int tilesM, int tilesN, int XGN, int expert) {
    constexpr int BN = NR * 32;
    constexpr int NRP = NR / NPH;           // n-frags per phase (4)
    constexpr int BIN = BN / 128;           // B stage insts (2 or 1)
    constexpr int LPT = 2 + BIN;            // stage insts / thread / K-tile
    constexpr int AELEMS = 256 * 32;
    constexpr int BELEMS = BN * 32;
    __shared__ __align__(16) bf16 lds[3][AELEMS + BELEMS];

    const int tid = threadIdx.x;
    const int wave = tid >> 6, lane = tid & 63;
    const int wm = wave >> 1, wn = wave & 1;
    const int r = lane & 15, kg = lane >> 4;

    // ---- 2-D XCD-aware tile mapping
    const int xcd = blockIdx.x & 7, slot = blockIdx.x >> 3;
    const int XGM = 8 / XGN;
    const int rm = tilesM / XGM, rn = tilesN / XGN;
    const int g = slot >> 5, u = slot & 31;
    const int gpr = rn >> 3;
    const int gm = (g / gpr) * 4 + (u >> 3);
    const int gn = (g % gpr) * 8 + (u & 7);
    const int tm = (xcd / XGN) * rm + gm;
    const int tn = (xcd % XGN) * rn + gn;

    const bf16* gA = A + (size_t)tm * 256 * lda;
    const bf16* gB = BT + (size_t)tn * BN * ldb;

    f32x4 acc[4][NR];
#pragma unroll
    for (int m = 0; m < 4; ++m)
#pragma unroll
        for (int n = 0; n < NR; ++n) acc[m][n] = (f32x4){0.f, 0.f, 0.f, 0.f};

    auto stageA = [&](int t) {
        bf16* Ab = lds[t % 3];
#pragma unroll
        for (int j = 0; j < 2; ++j) {
            int c = j * 512 + tid;
            int R = c >> 2, kc = (c & 3) ^ ((R >> 1) & 3);
            gload16(gA + (size_t)R * lda + t * 32 + kc * 8, Ab + (j * 512 + wave * 64) * 8);
        }
    };
    auto stageB = [&](int t) {
        bf16* Bb = lds[t % 3] + AELEMS;
#pragma unroll
        for (int j = 0; j < BIN; ++j) {
            int c = j * 512 + tid;
            int R = c >> 2, kc = (c & 3) ^ ((R >> 1) & 3);
            gload16(gB + (size_t)R * ldb + t * 32 + kc * 8, Bb + (j * 512 + wave * 64) * 8);
        }
    };

    // prologue: prefetch tiles 0,1
    stageA(0); stageB(0);
    stageA(1); stageB(1);
    wait_vmcnt<LPT>();                      // tile 0 resident; tile 1 in flight
    __builtin_amdgcn_s_barrier();

    for (int t = 0; t < NT; ++t) {
        const bf16* Ab = lds[t % 3];
        const bf16* Bb = Ab + AELEMS;
        s16x8 afr[4], bfr[NR];

        // ---- phase 0: read all A-frags + first B chunk; stage A(t+2)
#pragma unroll
        for (int m = 0; m < 4; ++m) {
            int R = wm * 64 + m * 16 + r;
            afr[m] = *(const s16x8*)(Ab + R * 32 + ((kg ^ ((R >> 1) & 3)) * 8));
        }
#pragma unroll
        for (int n = 0; n < NRP; ++n) {
            int R = wn * (NR * 16) + n * 16 + r;
            bfr[n] = *(const s16x8*)(Bb + R * 32 + ((kg ^ ((R >> 1) & 3)) * 8));
        }
        if (t + 2 < NT) stageA(t + 2);
        if (NPH == 1 && t + 2 < NT) stageB(t + 2);
        __builtin_amdgcn_s_barrier();
        asm volatile("s_waitcnt lgkmcnt(0)" ::: "memory");
        __builtin_amdgcn_sched_barrier(0);
        __builtin_amdgcn_s_setprio(1);
#pragma unroll
        for (int m = 0; m < 4; ++m)
#pragma unroll
            for (int n = 0; n < NRP; ++n)
                acc[m][n] = __builtin_amdgcn_mfma_f32_16x16x32_bf16(afr[m], bfr[n], acc[m][n], 0, 0, 0);
        __builtin_amdgcn_s_setprio(0);

        if (NPH == 2) {
            __builtin_amdgcn_s_barrier();
            // ---- phase 1: read second B chunk; stage B(t+2)
#pragma unroll
            for (int n = NRP; n < NR; ++n) {
                int R = wn * (NR * 16) + n * 16 + r;
                bfr[n] = *(const s16x8*)(Bb + R * 32 + ((kg ^ ((R >> 1) & 3)) * 8));
            }
            if (t + 2 < NT) stageB(t + 2);
            __builtin_amdgcn_s_barrier();
            asm volatile("s_waitcnt lgkmcnt(0)" ::: "memory");
            __builtin_amdgcn_sched_barrier(0);
            __builtin_amdgcn_s_setprio(1);
#pragma unroll
            for (int m = 0; m < 4; ++m)
#pragma unroll
                for (int n = NRP; n < NR; ++n)
                    acc[m][n] = __builtin_amdgcn_mfma_f32_16x16x32_bf16(afr[m], bfr[n], acc[m][n], 0, 0, 0);
            __builtin_amdgcn_s_setprio(0);
        }

        // ---- K-tile boundary: counted drain for tile t+1 (never 0 mid-loop)
        if (t + 1 < NT) {
            if (t + 2 < NT) wait_vmcnt<LPT>();
            else            wait_vmcnt<0>();
            __builtin_amdgcn_s_barrier();
        }
    }

    // ---- epilogue. C/D layout: col = lane&15 (r), row = kg*4 + j
    const size_t row0 = (size_t)tm * 256 + wm * 64;
    const int col0 = tn * BN + wn * (NR * 16);
    if (MODE == 1) {
        bf16* H = (bf16*)Cout;
#pragma unroll
        for (int n = 0; n < NR; ++n) {
            int cc = col0 + n * 16 + r;
            float bv = bias[cc];
#pragma unroll
            for (int m = 0; m < 4; ++m) {
#pragma unroll
                for (int j = 0; j < 4; ++j) {
                    size_t rr = row0 + m * 16 + kg * 4 + j;
                    float v = acc[m][n][j] + bv;
                    v = v > 0.f ? v : 0.f;
                    H[rr * (size_t)ldc + cc] = __float2bfloat16(v);
                }
            }
        }
    } else {
        float* O = (float*)Cout;
#pragma unroll
        for (int m = 0; m < 4; ++m) {
#pragma unroll
            for (int j = 0; j < 4; ++j) {
                size_t rr = row0 + m * 16 + kg * 4 + j;
                float wv = wts[rr * NEXP + expert];
#pragma unroll
                for (int n = 0; n < NR; ++n) {
                    int cc = col0 + n * 16 + r;
                    O[rr * (size_t)ldc + cc] += wv * acc[m][n][j];
                }
            }
        }
    }
}

// ---------------------------------------------------------------- launch
extern "C" void kernel_launch(void* const* d_in, const int* in_sizes, int n_in,
                              void* d_out, int out_size, void* d_ws, size_t ws_size,
                              hipStream_t stream) {
    const float* x  = (const float*)d_in[0];
    const float* Wg = (const float*)d_in[1];
    const float* bg = (const float*)d_in[2];
    const float* W1 = (const float*)d_in[3];
    const float* b1 = (const float*)d_in[4];
    const float* W2 = (const float*)d_in[5];
    const float* b2 = (const float*)d_in[6];
    float* out = (float*)d_out;

    char* ws = (char*)d_ws;
    bf16* xb   = (bf16*)(ws);                          // 16 MiB  [N][D]
    bf16* W1T  = (bf16*)(ws + (16ull << 20));          // 64 MiB  [E][H][D]
    bf16* W2T  = (bf16*)(ws + (80ull << 20));          // 64 MiB  [E][D][H]
    bf16* Hb   = (bf16*)(ws + (144ull << 20));         // 64 MiB  [N][H] (one expert)
    float* wts = (float*)(ws + (208ull << 20));        // 256 KiB [N][E]

    cvt_x_kernel<<<(NROW * DDIM / 4 + 255) / 256, 256, 0, stream>>>(x, xb, NROW * DDIM / 4);
    transpose_cvt_kernel<<<dim3(HDIM / 32, DDIM / 32, NEXP), 256, 0, stream>>>(W1, W1T, DDIM, HDIM);
    transpose_cvt_kernel<<<dim3(DDIM / 32, HDIM / 32, NEXP), 256, 0, stream>>>(W2, W2T, HDIM, DDIM);
    gate_kernel<<<NROW / 4, 256, 0, stream>>>(x, Wg, bg, wts);
    out_init_kernel<<<NROW * DDIM / 256, 256, 0, stream>>>(wts, b2, out);

    for (int e = 0; e < NEXP; ++e) {
        // GEMM1: M=8192, N=4096, K=1024 -> 32x16 tiles = 512 blocks; XCD rect 8x8
        gemm8<8, 2, 1><<<512, 512, 0, stream>>>(
            xb, W1T + (size_t)e * HDIM * DDIM, Hb, b1 + (size_t)e * HDIM, nullptr,
            DDIM, DDIM, HDIM, DDIM / 32, 32, 16, 2, e);
        // GEMM2: M=8192, N=1024, K=4096 -> 32x8 tiles = 256 blocks; XCD rect 4x8
        gemm8<4, 1, 2><<<256, 512, 0, stream>>>(
            Hb, W2T + (size_t)e * DDIM * HDIM, out, nullptr, wts,
            HDIM, HDIM, DDIM, HDIM / 32, 32, 8, 1, e);
    }
}